// Round 21
// baseline (213.373 us; speedup 1.0000x reference)
//
#include <hip/hip_runtime.h>
#include <hip/hip_bf16.h>
#include <math.h>

#define NB 8
#define NH 8
#define NS 1024
#define NE 512
#define NA 64
#define NBH (NB*NH)

typedef short s8v __attribute__((ext_vector_type(8)));   // 8 bf16 (4 VGPRs)
typedef float f4v __attribute__((ext_vector_type(4)));   // 4 f32 accum
typedef float f16v __attribute__((ext_vector_type(16))); // 16 f32 accum (32x32)
typedef unsigned short u4v __attribute__((ext_vector_type(4)));  // 4 bf16 (8B)

#define MFMA16(a,b,c) __builtin_amdgcn_mfma_f32_16x16x32_bf16((a),(b),(c),0,0,0)
#define MFMA32(a,b,c) __builtin_amdgcn_mfma_f32_32x32x16_bf16((a),(b),(c),0,0,0)

static __device__ __forceinline__ unsigned short f2bf(float f) {
    union { float f; unsigned u; } c; c.f = f;
    unsigned r = c.u + 0x7FFF + ((c.u >> 16) & 1);   // RNE
    return (unsigned short)(r >> 16);
}
// native HW conversion (RNE, same rounding)
static __device__ __forceinline__ unsigned short f2bf_hw(float f) {
    __hip_bfloat16 h = __float2bfloat16(f);
    return *(unsigned short*)&h;
}
static __device__ __forceinline__ s8v ld8(const unsigned short* p) {
    return *(const s8v*)p;
}
static __device__ __forceinline__ void gload16(const unsigned short* g, unsigned short* l) {
    __builtin_amdgcn_global_load_lds(
        (const __attribute__((address_space(1))) unsigned char*)g,
        (__attribute__((address_space(3))) unsigned char*)l, 16, 0, 0);
}

// stage a 128-row x 64-ush tile into 16KB LDS, linear dest (256 threads).
static __device__ __forceinline__ void stage_tile(
    const unsigned short* src, size_t stride, int k0,
    unsigned short* lds, int tid)
{
    int w = tid >> 6, l = tid & 63;
    #pragma unroll
    for (int c = 0; c < 4; ++c) {
        int chunk = w * 4 + c;
        int row = chunk * 8 + (l >> 3);
        gload16(src + (size_t)row * stride + k0 + (l & 7) * 8,
                lds + chunk * 512 + l * 8);
    }
}

// ---------------- K1: embed+LN wave-per-row (blocks 0..2047) | vectorized cvt (rest) ----------------
__global__ __launch_bounds__(256) void k_prep(
    const int* __restrict__ x, const float* __restrict__ emb,
    const float* __restrict__ gamma, const float* __restrict__ beta,
    const float* __restrict__ Wq, const float* __restrict__ Wk,
    const float* __restrict__ Wv,
    unsigned short* __restrict__ hb,
    unsigned short* __restrict__ wqb, unsigned short* __restrict__ wkb,
    unsigned short* __restrict__ wvb, int nqk, int nv)
{
    if (blockIdx.x < (NB * NS) / 4) {
        // one wave per row, 4 rows per block; no barriers, no LDS
        int w = threadIdx.x >> 6, l = threadIdx.x & 63;
        int row = blockIdx.x * 4 + w;
        int tok = x[row];
        const float4* e4 = (const float4*)(emb + (size_t)tok * NE);
        float4 a = e4[l], b = e4[l + 64];
        float sum = a.x + a.y + a.z + a.w + b.x + b.y + b.z + b.w;
        float ssq = a.x*a.x + a.y*a.y + a.z*a.z + a.w*a.w
                  + b.x*b.x + b.y*b.y + b.z*b.z + b.w*b.w;
        #pragma unroll
        for (int o = 32; o > 0; o >>= 1) {
            sum += __shfl_xor(sum, o);
            ssq += __shfl_xor(ssq, o);
        }
        float mu = sum / NE;
        float var = ssq / NE - mu * mu;
        float rstd = rsqrtf(var + 1e-5f);
        const float4* g4 = (const float4*)gamma;
        const float4* b4 = (const float4*)beta;
        float4 g0 = g4[l], g1 = g4[l + 64];
        float4 be0 = b4[l], be1 = b4[l + 64];
        unsigned short* hr = hb + (size_t)row * NE;
        u4v o0, o1;
        o0[0] = f2bf((a.x - mu) * rstd * g0.x + be0.x);
        o0[1] = f2bf((a.y - mu) * rstd * g0.y + be0.y);
        o0[2] = f2bf((a.z - mu) * rstd * g0.z + be0.z);
        o0[3] = f2bf((a.w - mu) * rstd * g0.w + be0.w);
        o1[0] = f2bf((b.x - mu) * rstd * g1.x + be1.x);
        o1[1] = f2bf((b.y - mu) * rstd * g1.y + be1.y);
        o1[2] = f2bf((b.z - mu) * rstd * g1.z + be1.z);
        o1[3] = f2bf((b.w - mu) * rstd * g1.w + be1.w);
        *(u4v*)(hr + l * 4) = o0;
        *(u4v*)(hr + 256 + l * 4) = o1;
    } else {
        // vectorized cvt: 4 f32 in (float4), 4 bf16 out (8B) per thread
        int i4 = (blockIdx.x - (NB * NS) / 4) * 256 + threadIdx.x;   // float4 index
        int q4 = nqk >> 2, v4 = nv >> 2;
        const float4* src;
        unsigned short* dst;
        int j4;
        if (i4 < q4)            { src = (const float4*)Wq; dst = wqb; j4 = i4; }
        else if (i4 < 2 * q4)   { src = (const float4*)Wk; dst = wkb; j4 = i4 - q4; }
        else if (i4 < 2 * q4 + v4) { src = (const float4*)Wv; dst = wvb; j4 = i4 - 2 * q4; }
        else return;
        float4 f = src[j4];
        u4v o;
        o[0] = f2bf(f.x); o[1] = f2bf(f.y); o[2] = f2bf(f.z); o[3] = f2bf(f.w);
        *(u4v*)(dst + (size_t)j4 * 4) = o;
    }
}

// ---------------- K2: merged projections: QK (blocks 0..511) | V (512..2559) ----------------
__global__ __launch_bounds__(256) void k_proj(
    const unsigned short* __restrict__ hb, const unsigned short* __restrict__ wqb,
    const unsigned short* __restrict__ wkb, const unsigned short* __restrict__ wvb,
    unsigned short* __restrict__ qb, unsigned short* __restrict__ kbf,
    unsigned short* __restrict__ vtb)
{
    int tid = threadIdx.x;
    int w = tid >> 6, l = tid & 63;
    int lo = l & 15, hi = l >> 4;
    int wr = w >> 1, wc = w & 1;

    __shared__ __align__(16) unsigned short As[128 * 64];
    __shared__ __align__(16) unsigned short Bs[128 * 64];

    f4v acc[4][4];
    f4v z = {0.f, 0.f, 0.f, 0.f};
    #pragma unroll
    for (int i = 0; i < 4; ++i)
        #pragma unroll
        for (int j = 0; j < 4; ++j) acc[i][j] = z;

    if (blockIdx.x < 512) {
        // ---- Q/K projection ----
        int bid = blockIdx.x;
        int b2 = (bid & 7) * 64 + (bid >> 3);
        int st = b2 & 7, bh = b2 >> 3;
        int b = bh >> 3, hh = bh & 7;

        const unsigned short* asrc = hb + ((size_t)(b * NS) + st * 128) * NE;
        for (int kt = 0; kt < 8; ++kt) {
            int k0 = kt * 64;
            stage_tile(asrc, NE, k0, As, tid);
            {
                #pragma unroll
                for (int c = 0; c < 4; ++c) {
                    int chunk = w * 4 + c;
                    int row = chunk * 8 + (l >> 3);
                    const unsigned short* bsrc = (chunk < 8)
                        ? wqb + ((size_t)(hh * NA) + row) * NE
                        : wkb + ((size_t)(hh * NA) + row - 64) * NE;
                    gload16(bsrc + k0 + (l & 7) * 8, Bs + chunk * 512 + l * 8);
                }
            }
            __syncthreads();
            #pragma unroll
            for (int ks = 0; ks < 2; ++ks) {
                s8v af[4], bf[4];
                #pragma unroll
                for (int sub = 0; sub < 4; ++sub)
                    af[sub] = ld8(As + (wr * 64 + sub * 16 + lo) * 64 + ks * 32 + hi * 8);
                #pragma unroll
                for (int es = 0; es < 4; ++es)
                    bf[es] = ld8(Bs + (wc * 64 + es * 16 + lo) * 64 + ks * 32 + hi * 8);
                #pragma unroll
                for (int sub = 0; sub < 4; ++sub)
                    #pragma unroll
                    for (int es = 0; es < 4; ++es)
                        acc[sub][es] = MFMA16(af[sub], bf[es], acc[sub][es]);
            }
            __syncthreads();
        }
        unsigned short* dst = (wc == 0) ? qb : kbf;
        #pragma unroll
        for (int sub = 0; sub < 4; ++sub)
            #pragma unroll
            for (int es = 0; es < 4; ++es)
                #pragma unroll
                for (int i = 0; i < 4; ++i) {
                    int s = st * 128 + wr * 64 + sub * 16 + hi * 4 + i;
                    int a = es * 16 + lo;
                    dst[((size_t)bh * NS + s) * NA + a] = f2bf(acc[sub][es][i]);
                }
    } else {
        // ---- V projection -> vT ----
        int bid = blockIdx.x - 512;
        int b2 = (bid & 7) * 256 + (bid >> 3);
        int tt = b2 & 7;
        int et = (b2 >> 3) & 3;
        int bh = b2 >> 5;
        int b = bh >> 3, hh = bh & 7;

        const unsigned short* asrc = wvb + ((size_t)(hh * NE) + et * 128) * NE;
        const unsigned short* bsrc = hb + ((size_t)(b * NS) + tt * 128) * NE;
        for (int kt = 0; kt < 8; ++kt) {
            int k0 = kt * 64;
            stage_tile(asrc, NE, k0, As, tid);
            stage_tile(bsrc, NE, k0, Bs, tid);
            __syncthreads();
            #pragma unroll
            for (int ks = 0; ks < 2; ++ks) {
                s8v af[4], bf[4];
                #pragma unroll
                for (int sub = 0; sub < 4; ++sub)
                    af[sub] = ld8(As + (wr * 64 + sub * 16 + lo) * 64 + ks * 32 + hi * 8);
                #pragma unroll
                for (int es = 0; es < 4; ++es)
                    bf[es] = ld8(Bs + (wc * 64 + es * 16 + lo) * 64 + ks * 32 + hi * 8);
                #pragma unroll
                for (int sub = 0; sub < 4; ++sub)
                    #pragma unroll
                    for (int es = 0; es < 4; ++es)
                        acc[sub][es] = MFMA16(af[sub], bf[es], acc[sub][es]);
            }
            __syncthreads();
        }
        #pragma unroll
        for (int sub = 0; sub < 4; ++sub)
            #pragma unroll
            for (int es = 0; es < 4; ++es)
                #pragma unroll
                for (int i = 0; i < 4; ++i) {
                    int e_ = et * 128 + wr * 64 + sub * 16 + hi * 4 + i;
                    int t_ = tt * 128 + wc * 64 + es * 16 + lo;
                    vtb[((size_t)bh * NE + e_) * NS + t_] = f2bf(acc[sub][es][i]);
                }
    }
}

// ---------------- K3: FUSED minmax + scores -> sigmoid -> wt(LDS) -> PV(32x32) ----------------
// Pass 1 + scores: 16x16x32 chain, bitwise-identical weights to R20.
// PV: mfma_f32_32x32x16 (half the instructions, faster rate). A=W[q,t]:
// lane row=l&31, k=(l>>5)*8; B=V[t,e]: col=l&31 from vT (contiguous t);
// C: col=l&31, row=(r&3)+8*(r>>2)+4*(l>>5). Association over t changes ~ulp.
__global__ __launch_bounds__(512, 2) void k_attn_fused(
    const unsigned short* __restrict__ qb, const unsigned short* __restrict__ kbf,
    const unsigned short* __restrict__ vtb, float* __restrict__ out)
{
    int bid = blockIdx.x;                       // 512
    int b2 = (bid & 7) * 64 + (bid >> 3);       // bijective XCD swizzle; qt fast
    int qt = b2 & 7, bh = b2 >> 3;
    int s0 = qt * 128;
    int tid = threadIdx.x;
    int w = tid >> 6, l = tid & 63;
    int lo = l & 15, hi = l >> 4;
    int l31 = l & 31, lh = l >> 5;              // 32x32 lane decomposition

    __shared__ __align__(16) unsigned short Qs[128 * 64];     // 16 KiB, swizzled
    __shared__ __align__(16) unsigned short wt[2][128 * 128]; // 64 KiB, swizzled
    __shared__ float pmn[8][128], pmx[8][128];                // 8 KiB partials

    // fill Qs once: 1024 16B-chunks, XOR-swizzled by row (ds_write path)
    #pragma unroll
    for (int j = 0; j < 2; ++j) {
        int ch = j * 512 + tid;
        int row = ch >> 3, cc = ch & 7;
        s8v qv = ld8(qb + ((size_t)bh * NS + s0 + row) * NA + cc * 8);
        *(s8v*)(Qs + row * 64 + ((cc ^ (row & 7)) * 8)) = qv;
    }

    const unsigned short* kframe = kbf + (size_t)bh * NS * NA;
    const unsigned short* vbase = vtb + ((size_t)bh * NE + w * 64) * NS;

    auto loadK = [&](int t0, s8v& k0, s8v& k1) {
        const unsigned short* kp = kframe + (size_t)(t0 + w * 16 + lo) * NA + hi * 8;
        k0 = ld8(kp);
        k1 = ld8(kp + 32);
    };
    auto loadQ = [&](int sub, s8v& q0, s8v& q1) {
        int r = sub * 16 + lo;
        q0 = ld8(Qs + r * 64 + ((hi ^ (lo & 7)) * 8));
        q1 = ld8(Qs + r * 64 + (((hi + 4) ^ (lo & 7)) * 8));
    };

    f4v z = {0.f, 0.f, 0.f, 0.f};
    s8v kc0, kc1, kn0, kn1;

    // ---- pass 1: min/max over this wave's t-strips (exact, order-free) ----
    __syncthreads();          // Qs filled
    float mnp[8], mxp[8];
    #pragma unroll
    for (int sub = 0; sub < 8; ++sub) { mnp[sub] = 1e30f; mxp[sub] = -1e30f; }
    loadK(0, kc0, kc1);
    for (int it = 0; it < 8; ++it) {
        if (it < 7) loadK((it + 1) * 128, kn0, kn1);
        #pragma unroll
        for (int sub = 0; sub < 8; ++sub) {
            s8v q0, q1;
            loadQ(sub, q0, q1);
            f4v c = z;
            c = MFMA16(kc0, q0, c);    // A=K, B=Q -- identical chain to pass 2
            c = MFMA16(kc1, q1, c);
            mnp[sub] = fminf(fminf(fminf(fminf(mnp[sub], c[0]), c[1]), c[2]), c[3]);
            mxp[sub] = fmaxf(fmaxf(fmaxf(fmaxf(mxp[sub], c[0]), c[1]), c[2]), c[3]);
        }
        kc0 = kn0; kc1 = kn1;
    }
    #pragma unroll
    for (int sub = 0; sub < 8; ++sub) {
        mnp[sub] = fminf(mnp[sub], __shfl_xor(mnp[sub], 16));
        mnp[sub] = fminf(mnp[sub], __shfl_xor(mnp[sub], 32));
        mxp[sub] = fmaxf(mxp[sub], __shfl_xor(mxp[sub], 16));
        mxp[sub] = fmaxf(mxp[sub], __shfl_xor(mxp[sub], 32));
    }
    if (l < 16) {
        #pragma unroll
        for (int sub = 0; sub < 8; ++sub) {
            pmn[w][sub * 16 + l] = mnp[sub];
            pmx[w][sub * 16 + l] = mxp[sub];
        }
    }
    __syncthreads();          // partials visible
    float invv[8], n2v[8];
    #pragma unroll
    for (int sub = 0; sub < 8; ++sub) {
        int q = sub * 16 + lo;
        float mn = pmn[0][q], mx = pmx[0][q];
        #pragma unroll
        for (int j = 1; j < 8; ++j) {
            mn = fminf(mn, pmn[j][q]);
            mx = fmaxf(mx, pmx[j][q]);
        }
        float iv = __builtin_amdgcn_rcpf(mx - mn);
        invv[sub] = iv;
        n2v[sub] = -mn * iv;
    }

    f16v acc32[4][2];
    #pragma unroll
    for (int qs = 0; qs < 4; ++qs)
        #pragma unroll
        for (int es = 0; es < 2; ++es)
            #pragma unroll
            for (int r = 0; r < 16; ++r) acc32[qs][es][r] = 0.f;

    // swapped scores -> sigmoid -> wt[q][t] (swizzled); identical to R20
    int cw = w * 2 + (hi >> 1);
    int whalf = (hi & 1) * 4;
    auto scores = [&](s8v k0, s8v k1, unsigned short* wbuf) {
        #pragma unroll
        for (int sub = 0; sub < 8; ++sub) {
            s8v q0, q1;
            loadQ(sub, q0, q1);
            f4v c = z;
            c = MFMA16(k0, q0, c);     // A=K, B=Q
            c = MFMA16(k1, q1, c);
            u4v pk;
            #pragma unroll
            for (int i = 0; i < 4; ++i) {
                float sn = fmaf(c[i], invv[sub], n2v[sub]);
                float arg = fmaf(sn, -14.4269504089f, 7.2134752044f);
                float e = __builtin_amdgcn_exp2f(arg);
                pk[i] = f2bf_hw(__builtin_amdgcn_rcpf(1.f + e));
            }
            *(u4v*)(wbuf + (sub * 16 + lo) * 128 + ((cw ^ (lo & 7)) * 8) + whalf) = pk;
        }
    };

    // ---- pass 2 ----
    loadK(0, kc0, kc1);
    scores(kc0, kc1, wt[0]);
    for (int it = 0; it < 8; ++it) {
        int t0 = it * 128;
        if (it < 7) loadK(t0 + 128, kn0, kn1);      // prefetch; rides across barrier
        asm volatile("s_waitcnt lgkmcnt(0)" ::: "memory");  // own wt writes committed
        __builtin_amdgcn_s_barrier();                // raw: does NOT drain vmcnt
        __builtin_amdgcn_sched_barrier(0);
        // --- PV 32x32x16: wave's 128q x 64e += W(128x128) @ V(128x64) ---
        {
            const unsigned short* wb = wt[it & 1];
            #pragma unroll
            for (int ks = 0; ks < 8; ++ks) {        // K=16 steps over 128 t
                s8v bv[2];
                #pragma unroll
                for (int es = 0; es < 2; ++es)
                    bv[es] = ld8(vbase + (size_t)(es * 32 + l31) * NS
                                 + t0 + ks * 16 + lh * 8);
                #pragma unroll
                for (int qs = 0; qs < 4; ++qs) {
                    int row = qs * 32 + l31;        // row&7 == l&7
                    s8v aw = ld8(wb + row * 128 + (((ks * 2 + lh) ^ (l & 7)) * 8));
                    #pragma unroll
                    for (int es = 0; es < 2; ++es)
                        acc32[qs][es] = MFMA32(aw, bv[es], acc32[qs][es]);
                }
            }
        }
        if (it < 7) scores(kn0, kn1, wt[(it + 1) & 1]);  // other buffer; no barrier
    }
    #pragma unroll
    for (int qs = 0; qs < 4; ++qs)
        #pragma unroll
        for (int es = 0; es < 2; ++es)
            #pragma unroll
            for (int r = 0; r < 16; ++r) {
                int row = s0 + qs * 32 + (r & 3) + 8 * (r >> 2) + 4 * lh;
                out[((size_t)bh * NS + row) * NE + w * 64 + es * 32 + l31]
                    = acc32[qs][es][r];
            }
}

extern "C" void kernel_launch(void* const* d_in, const int* in_sizes, int n_in,
                              void* d_out, int out_size, void* d_ws, size_t ws_size,
                              hipStream_t stream) {
    const int*   x     = (const int*)d_in[0];
    const float* emb   = (const float*)d_in[1];
    const float* gamma = (const float*)d_in[2];
    const float* beta  = (const float*)d_in[3];
    const float* Wq    = (const float*)d_in[4];
    const float* Wk    = (const float*)d_in[5];
    const float* Wv    = (const float*)d_in[6];
    float* out = (float*)d_out;

    unsigned short* p = (unsigned short*)d_ws;
    unsigned short* hb  = p;  p += (size_t)NB * NS * NE;
    unsigned short* qb  = p;  p += (size_t)NBH * NS * NA;
    unsigned short* kb  = p;  p += (size_t)NBH * NS * NA;
    unsigned short* vtb = p;  p += (size_t)NBH * NS * NE;
    unsigned short* wqb = p;  p += (size_t)NH * NA * NE;
    unsigned short* wkb = p;  p += (size_t)NH * NA * NE;
    unsigned short* wvb = p;  p += (size_t)NH * NE * NE;

    const int nqk = NH * NA * NE, nv = NH * NE * NE;
    const int cvt_blocks = ((2 * nqk + nv) / 4 + 255) / 256;   // 2560
    k_prep<<<(NB * NS) / 4 + cvt_blocks, 256, 0, stream>>>(
        x, emb, gamma, beta, Wq, Wk, Wv, hb, wqb, wkb, wvb, nqk, nv);
    k_proj<<<512 + 2048, 256, 0, stream>>>(hb, wqb, wkb, wvb, qb, kb, vtb);
    k_attn_fused<<<512, 512, 0, stream>>>(qb, kb, vtb, out);
}

// Round 22
// 197.051 us; speedup vs baseline: 1.0828x; 1.0828x over previous
//
#include <hip/hip_runtime.h>
#include <hip/hip_bf16.h>
#include <math.h>

#define NB 8
#define NH 8
#define NS 1024
#define NE 512
#define NA 64
#define NBH (NB*NH)

typedef short s8v __attribute__((ext_vector_type(8)));   // 8 bf16 (4 VGPRs)
typedef float f4v __attribute__((ext_vector_type(4)));   // 4 f32 accum
typedef unsigned short u4v __attribute__((ext_vector_type(4)));  // 4 bf16 (8B)

#define MFMA16(a,b,c) __builtin_amdgcn_mfma_f32_16x16x32_bf16((a),(b),(c),0,0,0)

static __device__ __forceinline__ unsigned short f2bf(float f) {
    union { float f; unsigned u; } c; c.f = f;
    unsigned r = c.u + 0x7FFF + ((c.u >> 16) & 1);   // RNE
    return (unsigned short)(r >> 16);
}
// native HW conversion (RNE, same rounding)
static __device__ __forceinline__ unsigned short f2bf_hw(float f) {
    __hip_bfloat16 h = __float2bfloat16(f);
    return *(unsigned short*)&h;
}
static __device__ __forceinline__ s8v ld8(const unsigned short* p) {
    return *(const s8v*)p;
}
static __device__ __forceinline__ void gload16(const unsigned short* g, unsigned short* l) {
    __builtin_amdgcn_global_load_lds(
        (const __attribute__((address_space(1))) unsigned char*)g,
        (__attribute__((address_space(3))) unsigned char*)l, 16, 0, 0);
}

// stage a 128-row x 64-ush tile into 16KB LDS, linear dest (256 threads).
static __device__ __forceinline__ void stage_tile(
    const unsigned short* src, size_t stride, int k0,
    unsigned short* lds, int tid)
{
    int w = tid >> 6, l = tid & 63;
    #pragma unroll
    for (int c = 0; c < 4; ++c) {
        int chunk = w * 4 + c;
        int row = chunk * 8 + (l >> 3);
        gload16(src + (size_t)row * stride + k0 + (l & 7) * 8,
                lds + chunk * 512 + l * 8);
    }
}

// ---------------- K1: embed+LN (blocks 0..NB*NS-1) | vectorized weight cvt (rest) ----------------
__global__ __launch_bounds__(256) void k_prep(
    const int* __restrict__ x, const float* __restrict__ emb,
    const float* __restrict__ gamma, const float* __restrict__ beta,
    const float* __restrict__ Wq, const float* __restrict__ Wk,
    const float* __restrict__ Wv,
    unsigned short* __restrict__ hb,
    unsigned short* __restrict__ wqb, unsigned short* __restrict__ wkb,
    unsigned short* __restrict__ wvb, int nqk, int nv)
{
    if (blockIdx.x < NB * NS) {
        int row = blockIdx.x;
        int tok = x[row];
        const float* e = emb + (size_t)tok * NE;
        int t = threadIdx.x;
        float v0 = e[t], v1 = e[t + 256];
        float sum = v0 + v1, ssq = v0 * v0 + v1 * v1;
        #pragma unroll
        for (int o = 32; o > 0; o >>= 1) {
            sum += __shfl_xor(sum, o);
            ssq += __shfl_xor(ssq, o);
        }
        __shared__ float wsum[4], wssq[4];
        __shared__ float mu_s, rstd_s;
        int wid = t >> 6;
        if ((t & 63) == 0) { wsum[wid] = sum; wssq[wid] = ssq; }
        __syncthreads();
        if (t == 0) {
            float S1 = wsum[0] + wsum[1] + wsum[2] + wsum[3];
            float S2 = wssq[0] + wssq[1] + wssq[2] + wssq[3];
            float mu = S1 / NE;
            float var = S2 / NE - mu * mu;
            mu_s = mu;
            rstd_s = rsqrtf(var + 1e-5f);
        }
        __syncthreads();
        float mu = mu_s, rstd = rstd_s;
        unsigned short* hr = hb + (size_t)row * NE;
        hr[t]       = f2bf((v0 - mu) * rstd * gamma[t]       + beta[t]);
        hr[t + 256] = f2bf((v1 - mu) * rstd * gamma[t + 256] + beta[t + 256]);
    } else {
        // vectorized cvt: 4 f32 in (float4), 4 bf16 out (8B) per thread
        int i4 = (blockIdx.x - NB * NS) * 256 + threadIdx.x;   // float4 index
        int q4 = nqk >> 2, v4 = nv >> 2;
        const float4* src;
        unsigned short* dst;
        int j4;
        if (i4 < q4)            { src = (const float4*)Wq; dst = wqb; j4 = i4; }
        else if (i4 < 2 * q4)   { src = (const float4*)Wk; dst = wkb; j4 = i4 - q4; }
        else if (i4 < 2 * q4 + v4) { src = (const float4*)Wv; dst = wvb; j4 = i4 - 2 * q4; }
        else return;
        float4 f = src[j4];
        u4v o;
        o[0] = f2bf(f.x); o[1] = f2bf(f.y); o[2] = f2bf(f.z); o[3] = f2bf(f.w);
        *(u4v*)(dst + (size_t)j4 * 4) = o;
    }
}

// ---------------- K2: merged projections: QK (blocks 0..511) | V (512..2559) ----------------
__global__ __launch_bounds__(256) void k_proj(
    const unsigned short* __restrict__ hb, const unsigned short* __restrict__ wqb,
    const unsigned short* __restrict__ wkb, const unsigned short* __restrict__ wvb,
    unsigned short* __restrict__ qb, unsigned short* __restrict__ kbf,
    unsigned short* __restrict__ vtb)
{
    int tid = threadIdx.x;
    int w = tid >> 6, l = tid & 63;
    int lo = l & 15, hi = l >> 4;
    int wr = w >> 1, wc = w & 1;

    __shared__ __align__(16) unsigned short As[128 * 64];
    __shared__ __align__(16) unsigned short Bs[128 * 64];

    f4v acc[4][4];
    f4v z = {0.f, 0.f, 0.f, 0.f};
    #pragma unroll
    for (int i = 0; i < 4; ++i)
        #pragma unroll
        for (int j = 0; j < 4; ++j) acc[i][j] = z;

    if (blockIdx.x < 512) {
        // ---- Q/K projection ----
        int bid = blockIdx.x;
        int b2 = (bid & 7) * 64 + (bid >> 3);
        int st = b2 & 7, bh = b2 >> 3;
        int b = bh >> 3, hh = bh & 7;

        const unsigned short* asrc = hb + ((size_t)(b * NS) + st * 128) * NE;
        for (int kt = 0; kt < 8; ++kt) {
            int k0 = kt * 64;
            stage_tile(asrc, NE, k0, As, tid);
            {
                #pragma unroll
                for (int c = 0; c < 4; ++c) {
                    int chunk = w * 4 + c;
                    int row = chunk * 8 + (l >> 3);
                    const unsigned short* bsrc = (chunk < 8)
                        ? wqb + ((size_t)(hh * NA) + row) * NE
                        : wkb + ((size_t)(hh * NA) + row - 64) * NE;
                    gload16(bsrc + k0 + (l & 7) * 8, Bs + chunk * 512 + l * 8);
                }
            }
            __syncthreads();
            #pragma unroll
            for (int ks = 0; ks < 2; ++ks) {
                s8v af[4], bf[4];
                #pragma unroll
                for (int sub = 0; sub < 4; ++sub)
                    af[sub] = ld8(As + (wr * 64 + sub * 16 + lo) * 64 + ks * 32 + hi * 8);
                #pragma unroll
                for (int es = 0; es < 4; ++es)
                    bf[es] = ld8(Bs + (wc * 64 + es * 16 + lo) * 64 + ks * 32 + hi * 8);
                #pragma unroll
                for (int sub = 0; sub < 4; ++sub)
                    #pragma unroll
                    for (int es = 0; es < 4; ++es)
                        acc[sub][es] = MFMA16(af[sub], bf[es], acc[sub][es]);
            }
            __syncthreads();
        }
        unsigned short* dst = (wc == 0) ? qb : kbf;
        #pragma unroll
        for (int sub = 0; sub < 4; ++sub)
            #pragma unroll
            for (int es = 0; es < 4; ++es)
                #pragma unroll
                for (int i = 0; i < 4; ++i) {
                    int s = st * 128 + wr * 64 + sub * 16 + hi * 4 + i;
                    int a = es * 16 + lo;
                    dst[((size_t)bh * NS + s) * NA + a] = f2bf(acc[sub][es][i]);
                }
    } else {
        // ---- V projection -> vT ----
        int bid = blockIdx.x - 512;
        int b2 = (bid & 7) * 256 + (bid >> 3);
        int tt = b2 & 7;
        int et = (b2 >> 3) & 3;
        int bh = b2 >> 5;
        int b = bh >> 3, hh = bh & 7;

        const unsigned short* asrc = wvb + ((size_t)(hh * NE) + et * 128) * NE;
        const unsigned short* bsrc = hb + ((size_t)(b * NS) + tt * 128) * NE;
        for (int kt = 0; kt < 8; ++kt) {
            int k0 = kt * 64;
            stage_tile(asrc, NE, k0, As, tid);
            stage_tile(bsrc, NE, k0, Bs, tid);
            __syncthreads();
            #pragma unroll
            for (int ks = 0; ks < 2; ++ks) {
                s8v af[4], bf[4];
                #pragma unroll
                for (int sub = 0; sub < 4; ++sub)
                    af[sub] = ld8(As + (wr * 64 + sub * 16 + lo) * 64 + ks * 32 + hi * 8);
                #pragma unroll
                for (int es = 0; es < 4; ++es)
                    bf[es] = ld8(Bs + (wc * 64 + es * 16 + lo) * 64 + ks * 32 + hi * 8);
                #pragma unroll
                for (int sub = 0; sub < 4; ++sub)
                    #pragma unroll
                    for (int es = 0; es < 4; ++es)
                        acc[sub][es] = MFMA16(af[sub], bf[es], acc[sub][es]);
            }
            __syncthreads();
        }
        #pragma unroll
        for (int sub = 0; sub < 4; ++sub)
            #pragma unroll
            for (int es = 0; es < 4; ++es)
                #pragma unroll
                for (int i = 0; i < 4; ++i) {
                    int e_ = et * 128 + wr * 64 + sub * 16 + hi * 4 + i;
                    int t_ = tt * 128 + wc * 64 + es * 16 + lo;
                    vtb[((size_t)bh * NE + e_) * NS + t_] = f2bf(acc[sub][es][i]);
                }
    }
}

// ---------------- K3: FUSED minmax + scores -> sigmoid -> wt(LDS) -> PV ----------------
// R20 structure exactly; single change: s_setprio(1) around the PV MFMA
// cluster (T5 -- wave role-diversity exists post-barrier at 2 waves/SIMD).
__global__ __launch_bounds__(512, 2) void k_attn_fused(
    const unsigned short* __restrict__ qb, const unsigned short* __restrict__ kbf,
    const unsigned short* __restrict__ vtb, float* __restrict__ out)
{
    int bid = blockIdx.x;                       // 512
    int b2 = (bid & 7) * 64 + (bid >> 3);       // bijective XCD swizzle; qt fast
    int qt = b2 & 7, bh = b2 >> 3;
    int s0 = qt * 128;
    int tid = threadIdx.x;
    int w = tid >> 6, l = tid & 63;
    int lo = l & 15, hi = l >> 4;

    __shared__ __align__(16) unsigned short Qs[128 * 64];     // 16 KiB, swizzled
    __shared__ __align__(16) unsigned short wt[2][128 * 128]; // 64 KiB, swizzled
    __shared__ float pmn[8][128], pmx[8][128];                // 8 KiB partials

    // fill Qs once: 1024 16B-chunks, XOR-swizzled by row (ds_write path)
    #pragma unroll
    for (int j = 0; j < 2; ++j) {
        int ch = j * 512 + tid;
        int row = ch >> 3, cc = ch & 7;
        s8v qv = ld8(qb + ((size_t)bh * NS + s0 + row) * NA + cc * 8);
        *(s8v*)(Qs + row * 64 + ((cc ^ (row & 7)) * 8)) = qv;
    }

    const unsigned short* kframe = kbf + (size_t)bh * NS * NA;
    const unsigned short* vbase = vtb + ((size_t)bh * NE + w * 64) * NS;

    // K fragment for wave's 16-t strip of tile t0 (A-operand rows = t)
    auto loadK = [&](int t0, s8v& k0, s8v& k1) {
        const unsigned short* kp = kframe + (size_t)(t0 + w * 16 + lo) * NA + hi * 8;
        k0 = ld8(kp);
        k1 = ld8(kp + 32);
    };
    // Q fragments for q-row group sub from swizzled LDS
    auto loadQ = [&](int sub, s8v& q0, s8v& q1) {
        int r = sub * 16 + lo;
        q0 = ld8(Qs + r * 64 + ((hi ^ (lo & 7)) * 8));
        q1 = ld8(Qs + r * 64 + (((hi + 4) ^ (lo & 7)) * 8));
    };

    f4v z = {0.f, 0.f, 0.f, 0.f};
    s8v kc0, kc1, kn0, kn1;

    // ---- pass 1: min/max over this wave's t-strips (exact, order-free) ----
    __syncthreads();          // Qs filled
    float mnp[8], mxp[8];
    #pragma unroll
    for (int sub = 0; sub < 8; ++sub) { mnp[sub] = 1e30f; mxp[sub] = -1e30f; }
    loadK(0, kc0, kc1);
    for (int it = 0; it < 8; ++it) {
        if (it < 7) loadK((it + 1) * 128, kn0, kn1);
        #pragma unroll
        for (int sub = 0; sub < 8; ++sub) {
            s8v q0, q1;
            loadQ(sub, q0, q1);
            f4v c = z;
            c = MFMA16(kc0, q0, c);    // A=K, B=Q -- identical chain to pass 2
            c = MFMA16(kc1, q1, c);
            // linear chains -> v_min3/v_max3 fusion (exact)
            mnp[sub] = fminf(fminf(fminf(fminf(mnp[sub], c[0]), c[1]), c[2]), c[3]);
            mxp[sub] = fmaxf(fmaxf(fmaxf(fmaxf(mxp[sub], c[0]), c[1]), c[2]), c[3]);
        }
        kc0 = kn0; kc1 = kn1;
    }
    #pragma unroll
    for (int sub = 0; sub < 8; ++sub) {
        mnp[sub] = fminf(mnp[sub], __shfl_xor(mnp[sub], 16));
        mnp[sub] = fminf(mnp[sub], __shfl_xor(mnp[sub], 32));
        mxp[sub] = fmaxf(mxp[sub], __shfl_xor(mxp[sub], 16));
        mxp[sub] = fmaxf(mxp[sub], __shfl_xor(mxp[sub], 32));
    }
    if (l < 16) {
        #pragma unroll
        for (int sub = 0; sub < 8; ++sub) {
            pmn[w][sub * 16 + l] = mnp[sub];
            pmx[w][sub * 16 + l] = mxp[sub];
        }
    }
    __syncthreads();          // partials visible
    // per-q sigmoid coefficients: sn = fma(c, invv, n2v)
    float invv[8], n2v[8];
    #pragma unroll
    for (int sub = 0; sub < 8; ++sub) {
        int q = sub * 16 + lo;
        float mn = pmn[0][q], mx = pmx[0][q];
        #pragma unroll
        for (int j = 1; j < 8; ++j) {
            mn = fminf(mn, pmn[j][q]);
            mx = fmaxf(mx, pmx[j][q]);
        }
        float iv = __builtin_amdgcn_rcpf(mx - mn);
        invv[sub] = iv;
        n2v[sub] = -mn * iv;
    }

    f4v acc[8][4];
    #pragma unroll
    for (int sub = 0; sub < 8; ++sub)
        #pragma unroll
        for (int es = 0; es < 4; ++es) acc[sub][es] = z;

    // swapped scores -> sigmoid (2 fma + exp2 + rcp + native cvt) -> wt[q][t] (swizzled)
    int cw = w * 2 + (hi >> 1);                // write chunk (16B units)
    int whalf = (hi & 1) * 4;                  // 8B half within chunk
    auto scores = [&](s8v k0, s8v k1, unsigned short* wbuf) {
        #pragma unroll
        for (int sub = 0; sub < 8; ++sub) {
            s8v q0, q1;
            loadQ(sub, q0, q1);
            f4v c = z;
            c = MFMA16(k0, q0, c);     // A=K, B=Q
            c = MFMA16(k1, q1, c);
            u4v pk;
            #pragma unroll
            for (int i = 0; i < 4; ++i) {
                float sn = fmaf(c[i], invv[sub], n2v[sub]);
                float arg = fmaf(sn, -14.4269504089f, 7.2134752044f);
                float e = __builtin_amdgcn_exp2f(arg);
                pk[i] = f2bf_hw(__builtin_amdgcn_rcpf(1.f + e));
            }
            *(u4v*)(wbuf + (sub * 16 + lo) * 128 + ((cw ^ (lo & 7)) * 8) + whalf) = pk;
        }
    };

    // ---- pass 2: R14 schedule ----
    loadK(0, kc0, kc1);
    scores(kc0, kc1, wt[0]);
    for (int it = 0; it < 8; ++it) {
        int t0 = it * 128;
        if (it < 7) loadK(t0 + 128, kn0, kn1);      // prefetch; rides across barrier
        asm volatile("s_waitcnt lgkmcnt(0)" ::: "memory");  // own wt writes committed
        __builtin_amdgcn_s_barrier();                // raw: does NOT drain vmcnt
        __builtin_amdgcn_sched_barrier(0);
        // --- PV: wave's 128q x 64e += W(128x128) @ V(128x64), setprio'd (T5) ---
        {
            const unsigned short* wb = wt[it & 1];
            __builtin_amdgcn_s_setprio(1);
            #pragma unroll
            for (int ks = 0; ks < 4; ++ks) {
                s8v bv[4];
                #pragma unroll
                for (int es = 0; es < 4; ++es)
                    bv[es] = ld8(vbase + (size_t)(es * 16 + lo) * NS + t0 + ks * 32 + hi * 8);
                #pragma unroll
                for (int sub = 0; sub < 8; ++sub) {
                    s8v aw = ld8(wb + (sub * 16 + lo) * 128 + (((ks * 4 + hi) ^ (lo & 7)) * 8));
                    #pragma unroll
                    for (int es = 0; es < 4; ++es)
                        acc[sub][es] = MFMA16(aw, bv[es], acc[sub][es]);
                }
            }
            __builtin_amdgcn_s_setprio(0);
        }
        if (it < 7) scores(kn0, kn1, wt[(it + 1) & 1]);  // other buffer; no barrier
    }
    #pragma unroll
    for (int sub = 0; sub < 8; ++sub)
        #pragma unroll
        for (int es = 0; es < 4; ++es)
            #pragma unroll
            for (int i = 0; i < 4; ++i)
                out[((size_t)bh * NS + s0 + sub * 16 + hi * 4 + i) * NE
                    + w * 64 + es * 16 + lo] = acc[sub][es][i];
}

extern "C" void kernel_launch(void* const* d_in, const int* in_sizes, int n_in,
                              void* d_out, int out_size, void* d_ws, size_t ws_size,
                              hipStream_t stream) {
    const int*   x     = (const int*)d_in[0];
    const float* emb   = (const float*)d_in[1];
    const float* gamma = (const float*)d_in[2];
    const float* beta  = (const float*)d_in[3];
    const float* Wq    = (const float*)d_in[4];
    const float* Wk    = (const float*)d_in[5];
    const float* Wv    = (const float*)d_in[6];
    float* out = (float*)d_out;

    unsigned short* p = (unsigned short*)d_ws;
    unsigned short* hb  = p;  p += (size_t)NB * NS * NE;
    unsigned short* qb  = p;  p += (size_t)NBH * NS * NA;
    unsigned short* kb  = p;  p += (size_t)NBH * NS * NA;
    unsigned short* vtb = p;  p += (size_t)NBH * NS * NE;
    unsigned short* wqb = p;  p += (size_t)NH * NA * NE;
    unsigned short* wkb = p;  p += (size_t)NH * NA * NE;
    unsigned short* wvb = p;  p += (size_t)NH * NE * NE;

    const int nqk = NH * NA * NE, nv = NH * NE * NE;
    const int cvt_blocks = ((2 * nqk + nv) / 4 + 255) / 256;   // 2560
    k_prep<<<NB * NS + cvt_blocks, 256, 0, stream>>>(
        x, emb, gamma, beta, Wq, Wk, Wv, hb, wqb, wkb, wvb, nqk, nv);
    k_proj<<<512 + 2048, 256, 0, stream>>>(hb, wqb, wkb, wvb, qb, kb, vtb);
    k_attn_fused<<<512, 512, 0, stream>>>(qb, kb, vtb, out);
}